// Round 2
// baseline (2105.058 us; speedup 1.0000x reference)
//
#include <hip/hip_runtime.h>

typedef __bf16 bf16;
typedef __bf16 bf16x8 __attribute__((ext_vector_type(8)));
typedef float  f32x4  __attribute__((ext_vector_type(4)));

#define N_EMBD 1024
#define HEADS 16
#define DIM_HEAD 64

// ---------------------------------------------------------------- helpers

__device__ __forceinline__ void async_load16(const bf16* g, bf16* l) {
    __builtin_amdgcn_global_load_lds(
        (const __attribute__((address_space(1))) void*)g,
        (__attribute__((address_space(3))) void*)l, 16, 0, 0);
}

__device__ __forceinline__ float gelu_f(float x) {
    const float c = 0.7978845608028654f; // sqrt(2/pi)
    float u = c * (x + 0.044715f * x * x * x);
    return 0.5f * x * (1.0f + tanhf(u));
}

// ---------------------------------------------------------------- f32 -> bf16 convert

__global__ __launch_bounds__(256) void cvt_f32_bf16(const float* __restrict__ in,
                                                    bf16* __restrict__ out, int n) {
    int i = (blockIdx.x * 256 + threadIdx.x) * 8;
    if (i >= n) return;
    bf16x8 v;
    #pragma unroll
    for (int j = 0; j < 8; j++) v[j] = (bf16)in[i + j];
    *(bf16x8*)&out[i] = v;
}

// ---------------------------------------------------------------- transpose: f32 [R,C] -> bf16 [C,R]

__global__ __launch_bounds__(256) void transpose_k(const float* __restrict__ in,
                                                   bf16* __restrict__ out, int R, int C) {
    __shared__ bf16 tile[32][33];
    int c0 = blockIdx.x * 32, r0 = blockIdx.y * 32;
    int tx = threadIdx.x, ty = threadIdx.y; // (32,8)
    #pragma unroll
    for (int j = 0; j < 4; j++)
        tile[ty + j * 8][tx] = (bf16)in[(size_t)(r0 + ty + j * 8) * C + c0 + tx];
    __syncthreads();
    #pragma unroll
    for (int j = 0; j < 4; j++)
        out[(size_t)(c0 + ty + j * 8) * R + r0 + tx] = tile[tx][ty + j * 8];
}

// ---------------------------------------------------------------- LayerNorm: fp32 in -> bf16 out

__global__ __launch_bounds__(256) void ln_kernel(const float* __restrict__ x,
                                                 const float* __restrict__ w,
                                                 const float* __restrict__ b,
                                                 bf16* __restrict__ out) {
    int row = blockIdx.x;
    int tid = threadIdx.x;
    const float* xr = x + (size_t)row * N_EMBD;
    float4 v = *(const float4*)&xr[tid * 4];
    float s  = v.x + v.y + v.z + v.w;
    float s2 = v.x * v.x + v.y * v.y + v.z * v.z + v.w * v.w;
    #pragma unroll
    for (int off = 32; off >= 1; off >>= 1) {
        s  += __shfl_down(s, off);
        s2 += __shfl_down(s2, off);
    }
    __shared__ float red[8];
    int wave = tid >> 6, lane = tid & 63;
    if (lane == 0) { red[wave] = s; red[4 + wave] = s2; }
    __syncthreads();
    s  = red[0] + red[1] + red[2] + red[3];
    s2 = red[4] + red[5] + red[6] + red[7];
    float mu  = s * (1.0f / N_EMBD);
    float var = s2 * (1.0f / N_EMBD) - mu * mu;
    float r = 1.0f / sqrtf(var + 1e-5f);
    bf16* orow = out + (size_t)row * N_EMBD;
    float vv[4] = {v.x, v.y, v.z, v.w};
    #pragma unroll
    for (int j = 0; j < 4; j++) {
        int c = tid * 4 + j;
        float y = (vv[j] - mu) * r * w[c] + b[c];
        orow[c] = (bf16)y;
    }
}

// ---------------------------------------------------------------- GEMM 256x256 8-wave, counted-vmcnt pipeline
// C[M,N] = A[M,K] * B[N,K]^T.  BK=64, 512 threads = 8 waves (2M x 4N),
// per-wave output 128x64.  LDS: double-buffered A[2][256][64] + B[2][256][64]
// = 128 KiB (dynamic shared).  Schedule per K-tile:
//   tile-top: issue next tile's 8 global_load_lds, s_waitcnt vmcnt(8)
//             (awaits CURRENT tile's loads, next tile's stay in flight -> T4),
//             raw s_barrier.
//   4 phases (C-quadrants), each: ds_read frags -> setprio(1) 16xMFMA
//             setprio(0) -> sched_barrier(0) -> s_barrier.
// T2 XOR swizzle (both-sides, rule 21): source k-chunk ^= (row&7) at staging
// (LDS dest linear for global_load_lds), read column chunk ^= (row&7).
// Verified conflict-free in round 1 (SQ_LDS_BANK_CONFLICT -> 0).
// M not divisible by 256: staging row clamped to M-1, stores guarded.

__global__ __launch_bounds__(512, 2) void gemm_bt256(
    const bf16* __restrict__ A, const bf16* __restrict__ B,
    bf16* __restrict__ Cout, float* __restrict__ Cacc,
    const float* __restrict__ bias,
    int M, int N, int K, int ldc, int act, int gn)
{
    extern __shared__ __align__(16) bf16 smem[];
    bf16 (*As)[256][64] = (bf16(*)[256][64])smem;
    bf16 (*Bs)[256][64] = (bf16(*)[256][64])(smem + 2 * 256 * 64);

    const int tid = threadIdx.x;
    const int wv = tid >> 6, lane = tid & 63;
    const int l15 = lane & 15, g = lane >> 4;
    const int waveM = wv >> 2, waveN = wv & 3;   // 2 x 4

    // XCD-bijective swizzle (m204): consecutive swz on same XCD share A panels
    const int nwg = gridDim.x;
    const int bid = blockIdx.x;
    const int q = nwg >> 3, r8 = nwg & 7;
    const int xcd = bid & 7, idx = bid >> 3;
    const int swz = (xcd < r8 ? xcd * (q + 1) : r8 * (q + 1) + (xcd - r8) * q) + idx;
    const int tileM = (swz / gn) * 256;
    const int tileN = (swz % gn) * 256;

    const int NT = K >> 6;

    f32x4 acc[8][4];
    #pragma unroll
    for (int i = 0; i < 8; i++)
        #pragma unroll
        for (int j = 0; j < 4; j++) acc[i][j] = (f32x4)0.0f;

    const int rr = tid >> 3;       // staging row-within-64
    const int kc0 = tid & 7;       // staging k-chunk (pre-swizzle)

    auto stage = [&](int t2) {
        const int nb = t2 & 1;
        const int k0 = t2 << 6;
        #pragma unroll
        for (int j = 0; j < 4; ++j) {
            int row = j * 64 + rr;
            int kc = kc0 ^ (row & 7);
            int ar = tileM + row; if (ar >= M) ar = M - 1;   // clamp (per-lane src ok)
            async_load16(A + (size_t)ar * K + k0 + kc * 8,
                         &As[nb][0][0] + ((size_t)j * 512 + wv * 64) * 8);
        }
        #pragma unroll
        for (int j = 0; j < 4; ++j) {
            int row = j * 64 + rr;
            int kc = kc0 ^ (row & 7);
            async_load16(B + (size_t)(tileN + row) * K + k0 + kc * 8,
                         &Bs[nb][0][0] + ((size_t)j * 512 + wv * 64) * 8);
        }
    };

    stage(0);   // prologue: 8 loads outstanding

    for (int t = 0; t < NT; ++t) {
        const int cur = t & 1;
        __builtin_amdgcn_sched_barrier(0);
        if (t + 1 < NT) {
            stage(t + 1);                                   // +8 -> 16 outstanding
            __builtin_amdgcn_sched_barrier(0);
            asm volatile("s_waitcnt vmcnt(8)" ::: "memory"); // tile t landed; t+1 in flight
        } else {
            __builtin_amdgcn_sched_barrier(0);
            asm volatile("s_waitcnt vmcnt(0)" ::: "memory"); // last tile: full drain
        }
        __builtin_amdgcn_sched_barrier(0);
        __builtin_amdgcn_s_barrier();                        // all waves' loads landed
        __builtin_amdgcn_sched_barrier(0);

        bf16x8 a[4][2], b0[2][2], b1[2][2];

        // ---- phase 0: read A-half0 + B-half0, MFMA quad(0,0)
        #pragma unroll
        for (int mf = 0; mf < 4; ++mf)
            #pragma unroll
            for (int ks = 0; ks < 2; ++ks) {
                int r2 = waveM * 128 + mf * 16 + l15;
                a[mf][ks] = *(const bf16x8*)&As[cur][r2][(((ks << 2) + g) ^ (l15 & 7)) << 3];
            }
        #pragma unroll
        for (int nf = 0; nf < 2; ++nf)
            #pragma unroll
            for (int ks = 0; ks < 2; ++ks) {
                int r2 = waveN * 64 + nf * 16 + l15;
                b0[nf][ks] = *(const bf16x8*)&Bs[cur][r2][(((ks << 2) + g) ^ (l15 & 7)) << 3];
            }
        __builtin_amdgcn_s_setprio(1);
        #pragma unroll
        for (int mf = 0; mf < 4; ++mf)
            #pragma unroll
            for (int nf = 0; nf < 2; ++nf)
                #pragma unroll
                for (int ks = 0; ks < 2; ++ks)
                    acc[mf][nf] = __builtin_amdgcn_mfma_f32_16x16x32_bf16(a[mf][ks], b0[nf][ks], acc[mf][nf], 0, 0, 0);
        __builtin_amdgcn_s_setprio(0);
        __builtin_amdgcn_sched_barrier(0);
        __builtin_amdgcn_s_barrier();
        __builtin_amdgcn_sched_barrier(0);

        // ---- phase 1: read B-half1, MFMA quad(0,1)
        #pragma unroll
        for (int nf = 0; nf < 2; ++nf)
            #pragma unroll
            for (int ks = 0; ks < 2; ++ks) {
                int r2 = waveN * 64 + (2 + nf) * 16 + l15;
                b1[nf][ks] = *(const bf16x8*)&Bs[cur][r2][(((ks << 2) + g) ^ (l15 & 7)) << 3];
            }
        __builtin_amdgcn_s_setprio(1);
        #pragma unroll
        for (int mf = 0; mf < 4; ++mf)
            #pragma unroll
            for (int nf = 0; nf < 2; ++nf)
                #pragma unroll
                for (int ks = 0; ks < 2; ++ks)
                    acc[mf][2 + nf] = __builtin_amdgcn_mfma_f32_16x16x32_bf16(a[mf][ks], b1[nf][ks], acc[mf][2 + nf], 0, 0, 0);
        __builtin_amdgcn_s_setprio(0);
        __builtin_amdgcn_sched_barrier(0);
        __builtin_amdgcn_s_barrier();
        __builtin_amdgcn_sched_barrier(0);

        // ---- phase 2: read A-half1 (reuse a regs), MFMA quad(1,1)
        #pragma unroll
        for (int mf = 0; mf < 4; ++mf)
            #pragma unroll
            for (int ks = 0; ks < 2; ++ks) {
                int r2 = waveM * 128 + 64 + mf * 16 + l15;
                a[mf][ks] = *(const bf16x8*)&As[cur][r2][(((ks << 2) + g) ^ (l15 & 7)) << 3];
            }
        __builtin_amdgcn_s_setprio(1);
        #pragma unroll
        for (int mf = 0; mf < 4; ++mf)
            #pragma unroll
            for (int nf = 0; nf < 2; ++nf)
                #pragma unroll
                for (int ks = 0; ks < 2; ++ks)
                    acc[4 + mf][2 + nf] = __builtin_amdgcn_mfma_f32_16x16x32_bf16(a[mf][ks], b1[nf][ks], acc[4 + mf][2 + nf], 0, 0, 0);
        __builtin_amdgcn_s_setprio(0);
        __builtin_amdgcn_sched_barrier(0);
        __builtin_amdgcn_s_barrier();
        __builtin_amdgcn_sched_barrier(0);

        // ---- phase 3: pure MFMA quad(1,0) (a = A-half1, b0 still live)
        __builtin_amdgcn_s_setprio(1);
        #pragma unroll
        for (int mf = 0; mf < 4; ++mf)
            #pragma unroll
            for (int nf = 0; nf < 2; ++nf)
                #pragma unroll
                for (int ks = 0; ks < 2; ++ks)
                    acc[4 + mf][nf] = __builtin_amdgcn_mfma_f32_16x16x32_bf16(a[mf][ks], b0[nf][ks], acc[4 + mf][nf], 0, 0, 0);
        __builtin_amdgcn_s_setprio(0);
        __builtin_amdgcn_sched_barrier(0);
        __builtin_amdgcn_s_barrier();
        __builtin_amdgcn_sched_barrier(0);
    }

    // epilogue: frag (mf,nf), row = tileM + waveM*128 + mf*16 + g*4 + j, col = tileN + waveN*64 + nf*16 + l15
    const int row0 = tileM + waveM * 128 + (g << 2);
    const int col0 = tileN + waveN * 64 + l15;
    #pragma unroll
    for (int mf = 0; mf < 8; ++mf) {
        #pragma unroll
        for (int nf = 0; nf < 4; ++nf) {
            int cc = col0 + nf * 16;
            float bv = bias ? bias[cc] : 0.0f;
            #pragma unroll
            for (int j = 0; j < 4; ++j) {
                int rw = row0 + mf * 16 + j;
                if (rw < M) {
                    float v = acc[mf][nf][j] + bv;
                    if (act) v = gelu_f(v);
                    if (Cacc) Cacc[(size_t)rw * ldc + cc] += v;
                    else      Cout[(size_t)rw * ldc + cc] = (bf16)v;
                }
            }
        }
    }
}

// ---------------------------------------------------------------- MFMA flash attention
// One block (4 waves) per (b,h). Wave w owns q-rows [w*16, w*16+16). T<=64.

__global__ __launch_bounds__(256) void attn_mfma(
    const bf16* __restrict__ Q, int ldq,
    const bf16* __restrict__ K, const bf16* __restrict__ V, int ldkv,
    bf16* __restrict__ O, int ldo,
    int T, int S, float scale)
{
    const int b = blockIdx.x >> 4, h = blockIdx.x & 15;
    const int tid = threadIdx.x;
    const int wave = tid >> 6, lane = tid & 63;
    const int l15 = lane & 15, g = lane >> 4;

    __shared__ __align__(16) bf16 Ks[64][72];  // [s][d], padded pitch
    __shared__ __align__(16) bf16 Vt[64][72];  // [d][s], padded pitch
    __shared__ __align__(16) bf16 Ps[64][72];  // [q][s], padded pitch

    const int qm = wave * 16 + l15;
    const bf16* qrow = Q + (size_t)(b * T + (qm < T ? qm : 0)) * ldq + h * DIM_HEAD;
    bf16x8 aq[2];
    #pragma unroll
    for (int kk = 0; kk < 2; kk++) {
        bf16x8 t = *(const bf16x8*)&qrow[kk * 32 + g * 8];
        #pragma unroll
        for (int j = 0; j < 8; j++) t[j] = (bf16)((float)t[j] * scale);
        aq[kk] = t;
    }

    float m_run[4], l_run[4];
    f32x4 acc_o[4];
    #pragma unroll
    for (int r = 0; r < 4; r++) { m_run[r] = -1e30f; l_run[r] = 0.0f; acc_o[r] = (f32x4)0.0f; }

    for (int s0 = 0; s0 < S; s0 += 64) {
        __syncthreads();
        for (int i = tid; i < 512; i += 256) {
            int r = i >> 3, c = (i & 7) * 8;
            int s = s0 + r;
            if (s < S) {
                size_t gidx = (size_t)(b * S + s) * ldkv + h * DIM_HEAD + c;
                *(int4*)&Ks[r][c] = *(const int4*)&K[gidx];
                bf16x8 v = *(const bf16x8*)&V[gidx];
                #pragma unroll
                for (int j = 0; j < 8; j++) Vt[c + j][r] = v[j];
            } else {
                int4 z; z.x = z.y = z.z = z.w = 0;
                *(int4*)&Ks[r][c] = z;
                #pragma unroll
                for (int j = 0; j < 8; j++) Vt[c + j][r] = (bf16)0.0f;
            }
        }
        __syncthreads();

        f32x4 sc[4];
        #pragma unroll
        for (int jn = 0; jn < 4; jn++) {
            f32x4 s = (f32x4)0.0f;
            bf16x8 bk0 = *(const bf16x8*)&Ks[jn * 16 + l15][g * 8];
            bf16x8 bk1 = *(const bf16x8*)&Ks[jn * 16 + l15][32 + g * 8];
            s = __builtin_amdgcn_mfma_f32_16x16x32_bf16(aq[0], bk0, s, 0, 0, 0);
            s = __builtin_amdgcn_mfma_f32_16x16x32_bf16(aq[1], bk1, s, 0, 0, 0);
            sc[jn] = s;
        }
        #pragma unroll
        for (int jn = 0; jn < 4; jn++)
            if (s0 + jn * 16 + l15 >= S) sc[jn] = (f32x4)(-1e30f);

        float mx[4];
        #pragma unroll
        for (int r = 0; r < 4; r++)
            mx[r] = fmaxf(fmaxf(sc[0][r], sc[1][r]), fmaxf(sc[2][r], sc[3][r]));
        #pragma unroll
        for (int off = 1; off < 16; off <<= 1)
            #pragma unroll
            for (int r = 0; r < 4; r++) mx[r] = fmaxf(mx[r], __shfl_xor(mx[r], off));
        float al[4];
        #pragma unroll
        for (int r = 0; r < 4; r++) {
            float mn = fmaxf(m_run[r], mx[r]);
            al[r] = __expf(m_run[r] - mn);
            m_run[r] = mn;
        }
        float rs[4] = {0.f, 0.f, 0.f, 0.f};
        #pragma unroll
        for (int jn = 0; jn < 4; jn++)
            #pragma unroll
            for (int r = 0; r < 4; r++) {
                float p = __expf(sc[jn][r] - m_run[r]);
                sc[jn][r] = p;
                rs[r] += p;
            }
        #pragma unroll
        for (int off = 1; off < 16; off <<= 1)
            #pragma unroll
            for (int r = 0; r < 4; r++) rs[r] += __shfl_xor(rs[r], off);
        #pragma unroll
        for (int r = 0; r < 4; r++) l_run[r] = l_run[r] * al[r] + rs[r];
        #pragma unroll
        for (int jd = 0; jd < 4; jd++)
            #pragma unroll
            for (int r = 0; r < 4; r++) acc_o[jd][r] *= al[r];

        #pragma unroll
        for (int jn = 0; jn < 4; jn++)
            #pragma unroll
            for (int r = 0; r < 4; r++)
                Ps[wave * 16 + g * 4 + r][jn * 16 + l15] = (bf16)sc[jn][r];
        __syncthreads();

        #pragma unroll
        for (int kk = 0; kk < 2; kk++) {
            bf16x8 ap = *(const bf16x8*)&Ps[wave * 16 + l15][kk * 32 + g * 8];
            #pragma unroll
            for (int jd = 0; jd < 4; jd++) {
                bf16x8 bv = *(const bf16x8*)&Vt[jd * 16 + l15][kk * 32 + g * 8];
                acc_o[jd] = __builtin_amdgcn_mfma_f32_16x16x32_bf16(ap, bv, acc_o[jd], 0, 0, 0);
            }
        }
    }

    #pragma unroll
    for (int r = 0; r < 4; r++) {
        int qq = wave * 16 + g * 4 + r;
        if (qq < T) {
            float inv = 1.0f / l_run[r];
            bf16* orow = O + (size_t)(b * T + qq) * ldo + h * DIM_HEAD;
            #pragma unroll
            for (int jd = 0; jd < 4; jd++)
                orow[jd * 16 + l15] = (bf16)(acc_o[jd][r] * inv);
        }
    }
}

// ---------------------------------------------------------------- launch

extern "C" void kernel_launch(void* const* d_in, const int* in_sizes, int n_in,
                              void* d_out, int out_size, void* d_ws, size_t ws_size,
                              hipStream_t stream) {
    const int B = 256, T = 60, S_IMG = 197, S_PR = 77;
    const int MQ = B * T;              // 15360
    const int M_PR = B * S_PR;         // 19712
    const float scale = 0.125f;        // 64^-0.5

    const float* x_in   = (const float*)d_in[0];
    const float* img    = (const float*)d_in[1];
    const float* prompt = (const float*)d_in[2];
    const float* ln1w = (const float*)d_in[3],  *ln1b = (const float*)d_in[4];
    const float* ln2w = (const float*)d_in[5],  *ln2b = (const float*)d_in[6];
    const float* ln3w = (const float*)d_in[7],  *ln3b = (const float*)d_in[8];
    const float* ln4w = (const float*)d_in[9],  *ln4b = (const float*)d_in[10];
    const float* sa_bo = (const float*)d_in[15];
    const float* ia_bo = (const float*)d_in[20];
    const float* pa_bo = (const float*)d_in[25];
    const float* fc_b  = (const float*)d_in[27];
    const float* pj_b  = (const float*)d_in[29];

    char* ws = (char*)d_ws;
    float* x_f32 = (float*)ws;
    bf16*  h     = (bf16*)(ws + 62914560);
    bf16*  ao    = h;  // aliased: h dead before attention output is written
    bf16*  qkv   = (bf16*)(ws + 94371840);
    bf16*  Rkv   = (bf16*)(ws + 188743680);                 // kv / hidden
    bf16*  Rcv   = (bf16*)(ws + 188743680 + 103284736);     // img_bf / prompt_bf
    bf16*  wT    = (bf16*)(ws + 330760192);
    bf16*  hidden = Rkv;

    // --- transpose all weights f32 [K,N] -> bf16 [N,K] into wT
    struct TJ { int idx; size_t off; int R, C; };
    const TJ jobs[14] = {
        {11, 0,        1024, 1024},  // sa_wq  -> fused qkv [3072,1024]
        {12, 1048576,  1024, 1024},  // sa_wk
        {13, 2097152,  1024, 1024},  // sa_wv
        {14, 3145728,  1024, 1024},  // sa_wo
        {16, 4194304,  1024, 1024},  // ia_wq
        {17, 5242880,  768,  1024},  // ia_wk  -> fused kv [2048,768]
        {18, 6029312,  768,  1024},  // ia_wv
        {19, 6815744,  1024, 1024},  // ia_wo
        {21, 7864320,  1024, 1024},  // pa_wq
        {22, 8912896,  768,  1024},  // pa_wk
        {23, 9699328,  768,  1024},  // pa_wv
        {24, 10485760, 1024, 1024},  // pa_wo
        {26, 11534336, 1024, 4096},  // fc_w   -> [4096,1024]
        {28, 15728640, 4096, 1024},  // proj_w -> [1024,4096]
    };
    for (int i = 0; i < 14; i++) {
        dim3 g(jobs[i].C / 32, jobs[i].R / 32), blk(32, 8);
        transpose_k<<<g, blk, 0, stream>>>((const float*)d_in[jobs[i].idx], wT + jobs[i].off,
                                           jobs[i].R, jobs[i].C);
    }

    // residual init: x_f32 = x (f32 copy)
    hipMemcpyAsync(x_f32, x_in, (size_t)MQ * N_EMBD * 4, hipMemcpyDeviceToDevice, stream);

    auto gemm = [&](const bf16* Aa, const bf16* Bw, bf16* Co, float* Ca, const float* bias,
                    int M, int N, int K, int ldc, int act) {
        int gm = (M + 255) / 256, gn = N / 256;
        gemm_bt256<<<gm * gn, 512, 131072, stream>>>(Aa, Bw, Co, Ca, bias, M, N, K, ldc, act, gn);
    };

    // ---- self attention
    ln_kernel<<<MQ, 256, 0, stream>>>(x_f32, ln1w, ln1b, h);
    gemm(h, wT + 0, qkv, nullptr, nullptr, MQ, 3072, 1024, 3072, 0);
    attn_mfma<<<B * HEADS, 256, 0, stream>>>(qkv, 3072, qkv + 1024, qkv + 2048, 3072,
                                             ao, 1024, T, T, scale);
    gemm(ao, wT + 3145728, nullptr, x_f32, sa_bo, MQ, 1024, 1024, 1024, 0);

    // ---- image cross attention (K/V chunked over 2 batch halves of 128)
    ln_kernel<<<MQ, 256, 0, stream>>>(x_f32, ln2w, ln2b, h);
    gemm(h, wT + 4194304, qkv, nullptr, nullptr, MQ, 1024, 1024, 1024, 0);
    {
        const int BC = 128, Mc = BC * S_IMG; // 25216
        for (int c = 0; c < 2; c++) {
            const float* imgc = img + (size_t)c * Mc * 768;
            cvt_f32_bf16<<<(Mc * 768) / 2048, 256, 0, stream>>>(imgc, Rcv, Mc * 768);
            gemm(Rcv, wT + 5242880, Rkv, nullptr, nullptr, Mc, 2048, 768, 2048, 0);
            attn_mfma<<<BC * HEADS, 256, 0, stream>>>(
                qkv + (size_t)c * BC * T * 1024, 1024, Rkv, Rkv + 1024, 2048,
                ao + (size_t)c * BC * T * 1024, 1024, T, S_IMG, scale);
        }
    }
    gemm(ao, wT + 6815744, nullptr, x_f32, ia_bo, MQ, 1024, 1024, 1024, 0);

    // ---- prompt cross attention
    ln_kernel<<<MQ, 256, 0, stream>>>(x_f32, ln3w, ln3b, h);
    gemm(h, wT + 7864320, qkv, nullptr, nullptr, MQ, 1024, 1024, 1024, 0);
    cvt_f32_bf16<<<(M_PR * 768) / 2048, 256, 0, stream>>>(prompt, Rcv, M_PR * 768);
    gemm(Rcv, wT + 8912896, Rkv, nullptr, nullptr, M_PR, 2048, 768, 2048, 0);
    attn_mfma<<<B * HEADS, 256, 0, stream>>>(qkv, 1024, Rkv, Rkv + 1024, 2048,
                                             ao, 1024, T, S_PR, scale);
    gemm(ao, wT + 10485760, nullptr, x_f32, pa_bo, MQ, 1024, 1024, 1024, 0);

    // ---- MLP
    ln_kernel<<<MQ, 256, 0, stream>>>(x_f32, ln4w, ln4b, h);
    gemm(h, wT + 11534336, hidden, nullptr, fc_b, MQ, 4096, 1024, 4096, 1);
    gemm(hidden, wT + 15728640, nullptr, x_f32, pj_b, MQ, 1024, 4096, 1024, 0);

    // output (f32)
    hipMemcpyAsync(d_out, x_f32, (size_t)MQ * N_EMBD * 4, hipMemcpyDeviceToDevice, stream);
}